// Round 2
// baseline (166.147 us; speedup 1.0000x reference)
//
#include <hip/hip_runtime.h>

#define Wd 640
#define Hd 512
#define NB 32
#define TW 64
#define TH 16
#define RR 4
constexpr int TILES_X = Wd / TW;   // 10
constexpr int TILES_Y = Hd / TH;   // 32
constexpr float EPSC = 0.5f;

// ---------------- Kernel A: disparity warp (bilinear along x) ----------------
__global__ __launch_bounds__(256)
void warp_kernel(const float* __restrict__ disp, const float* __restrict__ pattern,
                 float* __restrict__ proj /* = d_out + 1, 4B-aligned only */)
{
    int gid = blockIdx.x * 256 + threadIdx.x;   // one thread per 4 px
    int n = gid * 4;                            // grid sized exactly
    float4 d4 = *(const float4*)(disp + n);
    int u = n % Wd;                             // W divisible by 4 -> same row
    int rowbase = ((n / Wd) % Hd) * Wd;
    float dv[4] = {d4.x, d4.y, d4.z, d4.w};
    #pragma unroll
    for (int j = 0; j < 4; ++j) {
        float x = (float)(u + j) - dv[j];
        x = fminf(fmaxf(x, 0.f), (float)(Wd - 1));
        float x0 = floorf(x);
        float w = x - x0;
        int i0 = (int)x0;
        int i1 = min(i0 + 1, Wd - 1);
        float g0 = pattern[rowbase + i0];
        float g1 = pattern[rowbase + i1];
        proj[n + j] = fmaf(w, g1 - g0, g0);     // == (1-w)*g0 + w*g1
    }
}

// ---------------- census term: |c(da) - c(db)| with ONE rcp ----------------
// c(x) = x/(eps+|x|)
// ca - cb = [eps*(da-db) + (da*|db| - db*|da|)] / ((eps+|da|)*(eps+|db|))
// (cross term is SIGNED: 2*sign(da)*|da||db| when signs differ, 0 otherwise)
__device__ __forceinline__ float census_term(float na, float nb, float ac, float bc)
{
    float da = na - ac;
    float db = nb - bc;
    float q  = fmaf(da, fabsf(db), -db * fabsf(da));     // da*|db| - db*|da|
    float num = fmaf(EPSC, da - db, q);
    float den = (EPSC + fabsf(da)) * (EPSC + fabsf(db)); // >= 0.25, rcp safe
    return fabsf(num) * __builtin_amdgcn_rcpf(den);
}

// ---------------- Kernel B: half-space census sum over 64x16 tiles ----------------
__global__ __launch_bounds__(256)
void census_kernel(const float* __restrict__ proj, const float* __restrict__ im,
                   float* __restrict__ partial)
{
    __shared__ float sa[TH + RR][TW + 2 * RR];  // 20 x 72 floats
    __shared__ float sb[TH + RR][TW + 2 * RR];

    const int tU = blockIdx.x, tV = blockIdx.y, b = blockIdx.z;
    const int tid = threadIdx.x;
    const float* pb = proj + (size_t)b * (Hd * Wd);
    const float* ib = im   + (size_t)b * (Hd * Wd);
    const int v0  = tV * TH;
    const int u0g = tU * TW - RR;               // global col of LDS col 0

    for (int idx = tid; idx < (TH + RR) * (TW + 2 * RR); idx += 256) {
        int r = idx / (TW + 2 * RR);
        int c = idx - r * (TW + 2 * RR);
        int gv = min(v0 + r, Hd - 1);           // only bottom halo (dh >= 0)
        int gu = min(max(u0g + c, 0), Wd - 1);  // clamp; masked in compute
        int off = gv * Wd + gu;
        sa[r][c] = pb[off];
        sb[r][c] = ib[off];
    }
    __syncthreads();

    const int ty = tid >> 4;                    // 0..15 (row in tile)
    const int tx = tid & 15;                    // 0..15 (group of 4 px)
    const int cu = RR + 4 * tx;                 // LDS col of px 0

    float a8[8], b8[8];                         // cols u0..u0+7 (center + dh=0 right)
    *(float4*)&a8[0] = *(const float4*)&sa[ty][cu];
    *(float4*)&a8[4] = *(const float4*)&sa[ty][cu + 4];
    *(float4*)&b8[0] = *(const float4*)&sb[ty][cu];
    *(float4*)&b8[4] = *(const float4*)&sb[ty][cu + 4];

    float acc = 0.f;
    const bool edge = (tU == 0) | (tU == TILES_X - 1) | (tV == TILES_Y - 1);
    const int ub = tU * TW + 4 * tx;            // image col of px 0
    const int v  = v0 + ty;

    if (!edge) {
        #pragma unroll
        for (int j = 0; j < 4; ++j)
            #pragma unroll
            for (int d = 1; d <= 4; ++d)
                acc += census_term(a8[j + d], b8[j + d], a8[j], b8[j]);
        #pragma unroll
        for (int dh = 1; dh <= RR; ++dh) {
            float ra[12], rb[12];               // cols u0-4 .. u0+7
            *(float4*)&ra[0] = *(const float4*)&sa[ty + dh][4 * tx];
            *(float4*)&ra[4] = *(const float4*)&sa[ty + dh][4 * tx + 4];
            *(float4*)&ra[8] = *(const float4*)&sa[ty + dh][4 * tx + 8];
            *(float4*)&rb[0] = *(const float4*)&sb[ty + dh][4 * tx];
            *(float4*)&rb[4] = *(const float4*)&sb[ty + dh][4 * tx + 4];
            *(float4*)&rb[8] = *(const float4*)&sb[ty + dh][4 * tx + 8];
            #pragma unroll
            for (int j = 0; j < 4; ++j)
                #pragma unroll
                for (int dw = -4; dw <= 4; ++dw)
                    acc += census_term(ra[j + dw + 4], rb[j + dw + 4], a8[j], b8[j]);
        }
    } else {
        #pragma unroll
        for (int j = 0; j < 4; ++j)
            #pragma unroll
            for (int d = 1; d <= 4; ++d) {
                float m = (ub + j + d < Wd) ? 1.f : 0.f;
                acc = fmaf(m, census_term(a8[j + d], b8[j + d], a8[j], b8[j]), acc);
            }
        #pragma unroll
        for (int dh = 1; dh <= RR; ++dh) {
            float ra[12], rb[12];
            *(float4*)&ra[0] = *(const float4*)&sa[ty + dh][4 * tx];
            *(float4*)&ra[4] = *(const float4*)&sa[ty + dh][4 * tx + 4];
            *(float4*)&ra[8] = *(const float4*)&sa[ty + dh][4 * tx + 8];
            *(float4*)&rb[0] = *(const float4*)&sb[ty + dh][4 * tx];
            *(float4*)&rb[4] = *(const float4*)&sb[ty + dh][4 * tx + 4];
            *(float4*)&rb[8] = *(const float4*)&sb[ty + dh][4 * tx + 8];
            float mv = (v + dh < Hd) ? 1.f : 0.f;
            #pragma unroll
            for (int j = 0; j < 4; ++j)
                #pragma unroll
                for (int dw = -4; dw <= 4; ++dw) {
                    int uc = ub + j + dw;
                    float m = (uc >= 0 && uc < Wd) ? mv : 0.f;
                    acc = fmaf(m, census_term(ra[j + dw + 4], rb[j + dw + 4], a8[j], b8[j]), acc);
                }
        }
    }

    // block reduction -> one partial per block (deterministic)
    #pragma unroll
    for (int o = 32; o; o >>= 1) acc += __shfl_down(acc, o);
    __shared__ float wsum[4];
    int wid = tid >> 6, lane = tid & 63;
    if (lane == 0) wsum[wid] = acc;
    __syncthreads();
    if (tid == 0) {
        float s = wsum[0] + wsum[1] + wsum[2] + wsum[3];
        partial[((int)blockIdx.z * gridDim.y + blockIdx.y) * gridDim.x + blockIdx.x] = s;
    }
}

// ---------------- Kernel C: final deterministic reduce ----------------
__global__ __launch_bounds__(1024)
void final_reduce(const float* __restrict__ partial, float* __restrict__ out)
{
    const int n = NB * TILES_Y * TILES_X;       // 10240
    double s = 0.0;
    for (int i = threadIdx.x; i < n; i += 1024) s += (double)partial[i];
    __shared__ double sm[1024];
    sm[threadIdx.x] = s;
    __syncthreads();
    for (int st = 512; st; st >>= 1) {
        if (threadIdx.x < st) sm[threadIdx.x] += sm[threadIdx.x + st];
        __syncthreads();
    }
    if (threadIdx.x == 0) {
        // val = 2 * S_half / (81 * B*H*W)   (half-space symmetry doubling)
        out[0] = (float)(sm[0] * (2.0 / (81.0 * (double)NB * Hd * Wd)));
    }
}

extern "C" void kernel_launch(void* const* d_in, const int* in_sizes, int n_in,
                              void* d_out, int out_size, void* d_ws, size_t ws_size,
                              hipStream_t stream)
{
    const float* disp    = (const float*)d_in[0];
    const float* im      = (const float*)d_in[1];
    const float* pattern = (const float*)d_in[2];
    float* out  = (float*)d_out;
    float* proj = out + 1;                      // output 1: pattern_proj
    float* partial = (float*)d_ws;              // 10240 floats scratch

    const int npx = NB * Hd * Wd;
    warp_kernel<<<npx / (256 * 4), 256, 0, stream>>>(disp, pattern, proj);

    dim3 grid(TILES_X, TILES_Y, NB);
    census_kernel<<<grid, 256, 0, stream>>>(proj, im, partial);

    final_reduce<<<1, 1024, 0, stream>>>(partial, out);
}